// Round 9
// baseline (1569.902 us; speedup 1.0000x reference)
//
#include <hip/hip_runtime.h>
#include <math.h>

#define Bsz  1024
#define Tlen 128
#define Hdim 512
#define NCLS 10
#define NDIG 3
#define G4   2048   // 4*H

typedef short s8v __attribute__((ext_vector_type(8)));    // 8 bf16 (4 VGPRs)
typedef float f16v __attribute__((ext_vector_type(16)));  // 32x32 mfma acc

// ---- workspace layout (bytes) ----
// W6 : 2 MB  bf16 frag chunks: uint4 idx = (wn*32+ks)*64 + lane, wn=0..63
//      lane l elem j: n = wn*32+(l&31) -> jp=n>>2,g=n&3, row=g*512+jp,
//      k = ks*16 + (l>>5)*8 + j      (serves as A-frag rows=n OR B-frag cols)
// gxd: 24 KB fp32 [d][jp*4+g] (padded to 32 KB)
// h0/h1: 1 MB bf16 each; per-chain 32 KB: uint4 idx = mt*2048 + ks*64 + l
//      elem j = h[b = l&31][k = ks*16 + (l>>5)*8 + j]   (32 rows x 512 k)
// gflags: 32 KB (32 chains x 8 producers, stride 32 ints): value t = h_t published
#define W6_OFF  0
#define GXD_OFF (2*1024*1024)
#define H0_OFF  (GXD_OFF + 32*1024)
#define H1_OFF  (H0_OFF + 1024*1024)
#define FLG_OFF (H1_OFF + 1024*1024)

static __device__ __forceinline__ unsigned short f2bf(float f) {
    unsigned int u = __float_as_uint(f);
    u = (u + 0x7FFFu + ((u >> 16) & 1u)) >> 16;   // RNE
    return (unsigned short)u;
}
static __device__ __forceinline__ float bf2f(unsigned short s) {
    return __uint_as_float(((unsigned int)s) << 16);
}
static __device__ __forceinline__ s8v u2s(uint4 v) {
    union { uint4 u; s8v s; } x; x.u = v; return x.s;
}

// ---- prep: W6 frag chunks (unchanged R5 layout) ----
__global__ __launch_bounds__(256) void prep_w6(const float* __restrict__ Wh,
                                               unsigned short* __restrict__ W6) {
    int idx = blockIdx.x * 256 + threadIdx.x;   // 0..131071
    int l  = idx & 63;
    int c  = idx >> 6;          // wn*32 + ks
    int ks = c & 31, wn = c >> 5;
    int n  = wn * 32 + (l & 31);
    int jp = n >> 2, g = n & 3;
    int row = g * Hdim + jp;
    int kb  = ks * 16 + (l >> 5) * 8;
    const float* src = &Wh[(size_t)row * Hdim + kb];
    unsigned int p0 = f2bf(src[0]) | ((unsigned int)f2bf(src[1]) << 16);
    unsigned int p1 = f2bf(src[2]) | ((unsigned int)f2bf(src[3]) << 16);
    unsigned int p2 = f2bf(src[4]) | ((unsigned int)f2bf(src[5]) << 16);
    unsigned int p3 = f2bf(src[6]) | ((unsigned int)f2bf(src[7]) << 16);
    ((uint4*)W6)[idx] = make_uint4(p0, p1, p2, p3);
}

__global__ __launch_bounds__(256) void prep_gxd(const float* __restrict__ emb,
                                                const float* __restrict__ Wx,
                                                const float* __restrict__ b,
                                                float* __restrict__ gxd) {
    int idx = blockIdx.x * 256 + threadIdx.x;
    if (idx >= NDIG * G4) return;
    int col = idx % G4;
    int d   = idx / G4;
    int jp  = col >> 2;
    int g   = col & 3;
    int row = g * Hdim + jp;
    gxd[idx] = emb[d * 2 + 0] * Wx[row * 2 + 0]
             + emb[d * 2 + 1] * Wx[row * 2 + 1]
             + b[row];
}

__global__ __launch_bounds__(256) void zero_state(float4* __restrict__ p, int n4) {
    int i = blockIdx.x * 256 + threadIdx.x;
    if (i < n4) p[i] = make_float4(0.f, 0.f, 0.f, 0.f);
}

// ---- persistent LSTM: dataflow-sync chains, NO barriers in the loop ----
// 256 blocks x 512 thr (1/CU). mt = blk&31 (chain: 32 rows), nt = blk>>5
// (n-window: 256 gate-cols = 64 jp). Chain of 8 blocks exchanges h via L3
// with per-producer flags. MFMA computes z^T = W.h^T so all 4 gates of a
// (b, jp) land in one lane -> wave-local epilogue, no z round-trip.
__global__ __launch_bounds__(512, 2) void lstm_persist(
    const uint4* __restrict__ W6, const float* __restrict__ gxd,
    const int* __restrict__ x, uint4* __restrict__ h0, uint4* __restrict__ h1,
    int* __restrict__ gflags, const float* __restrict__ Wp,
    const float* __restrict__ bp, float* __restrict__ out)
{
    __shared__ uint4 h_lds[2 * 2048];   // 64 KB  h B-frags, t-parity dbuf
    __shared__ float gxd_s[NDIG * G4];  // 24 KB
    __shared__ int   x_s[4096];         // 16 KB  [t][b_local]
    __shared__ int   cf[16];            // chunk flags [par*8+q] = t+1 when staged
    __shared__ int   done[2];           // per-parity epilogue-store counter

    const int tid  = threadIdx.x;
    const int w    = tid >> 6;          // wave 0..7
    const int lane = tid & 63;
    const int hi   = lane >> 5;
    const int bl   = lane & 31;         // batch row 0..31 (via C col)
    const int mt   = blockIdx.x & 31;
    const int nt   = blockIdx.x >> 5;

    // A-resident W fragments: wave n-window = nt*256 + w*32 (32 gate-cols)
    s8v wfrag[32];
    {
        const uint4* wq = W6 + (size_t)((nt * 8 + w) * 32) * 64 + lane;
#pragma unroll
        for (int ks = 0; ks < 32; ks++) wfrag[ks] = u2s(wq[ks * 64]);
    }
    // stage x (transposed) and gxd into LDS
    for (int i = tid; i < 4096; i += 512) {
        int b2 = i & 31, tt = i >> 5;
        x_s[tt * 32 + b2] = x[(mt * 32 + b2) * Tlen + tt];
    }
    for (int i = tid; i < NDIG * G4; i += 512) gxd_s[i] = gxd[i];
    if (tid < 16) cf[tid] = 0;
    if (tid < 2) done[tid] = 0;
    __syncthreads();   // one-time init sync only

    float c0 = 0.f, c1 = 0.f, c2 = 0.f, c3 = 0.f;
    const int jbase = nt * 64 + w * 8 + hi;           // jp for u: jbase + 2u
    // h-store (ull units): chunk ks = nt*4+(w>>1), q32 = w&1, then hi half
    const long hsull = ((long)mt * 2048 + (nt * 4 + (w >> 1)) * 64
                        + (w & 1) * 32 + bl) * 2 + hi;
    int* myflag = gflags + (mt * 8 + nt) * 32;
    const int* stgflag = gflags + (mt * 8 + w) * 32;

#pragma unroll 1
    for (int t = 0; t < Tlen; t++) {
        const int par = t & 1;
        const uint4* hr = par ? h1 : h0;   // h_t
        uint4*       hw = par ? h0 : h1;   // h_{t+1}

        // ---- staging duty: producer w's 4 KB k-slice -> LDS ----
        {
            while (__hip_atomic_load(stgflag, __ATOMIC_RELAXED,
                                     __HIP_MEMORY_SCOPE_AGENT) < t)
                __builtin_amdgcn_s_sleep(1);
            const unsigned long long* hr8 =
                (const unsigned long long*)(hr + mt * 2048);
            unsigned long long* hl8 =
                (unsigned long long*)(h_lds + par * 2048);
#pragma unroll
            for (int s = 0; s < 4; s++) {
                int o = (w * 4 + s) * 128 + lane * 2;
                unsigned long long a0 = __hip_atomic_load(hr8 + o,
                    __ATOMIC_RELAXED, __HIP_MEMORY_SCOPE_AGENT);
                unsigned long long a1 = __hip_atomic_load(hr8 + o + 1,
                    __ATOMIC_RELAXED, __HIP_MEMORY_SCOPE_AGENT);
                hl8[o]     = a0;
                hl8[o + 1] = a1;
            }
            asm volatile("s_waitcnt lgkmcnt(0)" ::: "memory");
            if (lane == 0)
                __hip_atomic_store(&cf[par * 8 + w], t + 1, __ATOMIC_RELAXED,
                                   __HIP_MEMORY_SCOPE_WORKGROUP);
        }

        // ---- K loop: z^T tile, chunks gated by LDS flags ----
        f16v acc = {0,0,0,0,0,0,0,0,0,0,0,0,0,0,0,0};
#pragma unroll
        for (int p2 = 0; p2 < 8; p2++) {
            int q = (w + p2) & 7;
            if (p2 > 0)
                while (__hip_atomic_load(&cf[par * 8 + q], __ATOMIC_RELAXED,
                                         __HIP_MEMORY_SCOPE_WORKGROUP) < t + 1) {}
#pragma unroll
            for (int s = 0; s < 4; s++) {
                s8v hf = u2s(h_lds[par * 2048 + (q * 4 + s) * 64 + lane]);
                acc = __builtin_amdgcn_mfma_f32_32x32x16_bf16(
                          wfrag[q * 4 + s], hf, acc, 0, 0, 0);
            }
        }

        // ---- wave-local epilogue: lane = (b=bl, jp = jbase+2u, all 4 gates) ----
        {
            int d = x_s[t * 32 + bl];
            float cc[4] = {c0, c1, c2, c3};
            unsigned short hh[4];
#pragma unroll
            for (int u = 0; u < 4; u++) {
                int jp = jbase + 2 * u;
                float4 g4 = *(const float4*)&gxd_s[d * G4 + jp * 4];
                float zg = acc[4*u+0] + g4.x;
                float zi = acc[4*u+1] + g4.y;
                float zf = acc[4*u+2] + g4.z;
                float zo = acc[4*u+3] + g4.w;
                float gv = 1.f - 2.f / (__expf(2.f * zg) + 1.f);
                float iv = 1.f / (1.f + __expf(-zi));
                float fv = 1.f / (1.f + __expf(-zf));
                float ov = 1.f / (1.f + __expf(-zo));
                float cn = gv * iv + cc[u] * fv;
                cc[u] = cn;
                hh[u] = f2bf((1.f - 2.f / (__expf(2.f * cn) + 1.f)) * ov);
            }
            c0 = cc[0]; c1 = cc[1]; c2 = cc[2]; c3 = cc[3];
            // repack even/odd jp across hi-halves -> contiguous 4x bf16
            unsigned int p01 = (unsigned int)hh[0] | ((unsigned int)hh[1] << 16);
            unsigned int p23 = (unsigned int)hh[2] | ((unsigned int)hh[3] << 16);
            unsigned int q01 = __shfl_xor(p01, 32);
            unsigned int q23 = __shfl_xor(p23, 32);
            unsigned long long hv;
            if (hi == 0) {   // jj 0..3 = [own0, peer0, own1, peer1]
                unsigned int lo2 = (p01 & 0xffffu) | ((q01 & 0xffffu) << 16);
                unsigned int hi2 = (p01 >> 16) | (q01 & 0xffff0000u);
                hv = (unsigned long long)lo2 | ((unsigned long long)hi2 << 32);
            } else {         // jj 4..7 = [peer2, own2, peer3, own3]
                unsigned int lo2 = (q23 & 0xffffu) | ((p23 & 0xffffu) << 16);
                unsigned int hi2 = (q23 >> 16) | (p23 & 0xffff0000u);
                hv = (unsigned long long)lo2 | ((unsigned long long)hi2 << 32);
            }
            __hip_atomic_store((unsigned long long*)hw + hsull, hv,
                               __ATOMIC_RELAXED, __HIP_MEMORY_SCOPE_AGENT);
        }

        // ---- publish: count 8 waves' drained stores, last one sets flag ----
        asm volatile("s_waitcnt vmcnt(0)" ::: "memory");
        if (lane == 0) {
            int old = atomicAdd(&done[par], 1);
            if (old == 7) {
                done[par] = 0;
                __hip_atomic_store(myflag, t + 1, __ATOMIC_RELAXED,
                                   __HIP_MEMORY_SCOPE_AGENT);
            }
        }
    }

    // ---- head (nt==0 blocks): p = h.Wp + bp, log_softmax for 32 rows ----
    if (nt != 0) return;
    if (tid < 8) {
        const int* gf = gflags + (mt * 8 + tid) * 32;
        while (__hip_atomic_load(gf, __ATOMIC_RELAXED,
                                 __HIP_MEMORY_SCOPE_AGENT) < Tlen)
            __builtin_amdgcn_s_sleep(1);
    }
    __syncthreads();
    float* wp_s = gxd_s;   // 20 KB into 24 KB region
    for (int i = tid; i < Hdim * NCLS; i += 512) wp_s[i] = Wp[i];
    __syncthreads();

    const unsigned long long* hf8 =
        (const unsigned long long*)(h0 + mt * 2048);   // h_128 in buf0
#pragma unroll
    for (int rr = 0; rr < 4; rr++) {
        int blr = w * 4 + rr;
        int b   = mt * 32 + blr;
        // lane covers k = lane*8..+7: u4 = (lane>>1)*64 + (lane&1)*32 + blr
        int u4 = (lane >> 1) * 64 + (lane & 1) * 32 + blr;
        unsigned long long lo = __hip_atomic_load(hf8 + u4 * 2,
            __ATOMIC_RELAXED, __HIP_MEMORY_SCOPE_AGENT);
        unsigned long long hi2 = __hip_atomic_load(hf8 + u4 * 2 + 1,
            __ATOMIC_RELAXED, __HIP_MEMORY_SCOPE_AGENT);
        union { unsigned long long q[2]; unsigned short s[8]; } hu;
        hu.q[0] = lo; hu.q[1] = hi2;
        float a[NCLS];
#pragma unroll
        for (int c = 0; c < NCLS; c++) a[c] = 0.f;
#pragma unroll
        for (int j = 0; j < 8; j++) {
            int k = lane * 8 + j;
            float hvv = bf2f(hu.s[j]);
#pragma unroll
            for (int c = 0; c < NCLS; c++) a[c] += hvv * wp_s[k * NCLS + c];
        }
#pragma unroll
        for (int off = 32; off > 0; off >>= 1) {
#pragma unroll
            for (int c = 0; c < NCLS; c++) a[c] += __shfl_down(a[c], off);
        }
        if (lane == 0) {
            float p[NCLS], m = -1e30f;
#pragma unroll
            for (int c = 0; c < NCLS; c++) { p[c] = a[c] + bp[c]; m = fmaxf(m, p[c]); }
            float s = 0.f;
#pragma unroll
            for (int c = 0; c < NCLS; c++) s += __expf(p[c] - m);
            float lse = m + logf(s);
#pragma unroll
            for (int c = 0; c < NCLS; c++) out[b * NCLS + c] = p[c] - lse;
        }
    }
}

extern "C" void kernel_launch(void* const* d_in, const int* in_sizes, int n_in,
                              void* d_out, int out_size, void* d_ws, size_t ws_size,
                              hipStream_t stream) {
    const int*   x   = (const int*)d_in[0];
    const float* emb = (const float*)d_in[1];
    const float* Wx  = (const float*)d_in[2];
    const float* Wh  = (const float*)d_in[3];
    const float* b   = (const float*)d_in[4];
    const float* Wp  = (const float*)d_in[5];
    const float* bp  = (const float*)d_in[6];
    float* out = (float*)d_out;
    char*  ws  = (char*)d_ws;

    unsigned short* W6  = (unsigned short*)(ws + W6_OFF);
    float*          gxd = (float*)(ws + GXD_OFF);
    uint4*          h0  = (uint4*)(ws + H0_OFF);
    uint4*          h1  = (uint4*)(ws + H1_OFF);
    int*            flg = (int*)(ws + FLG_OFF);

    prep_w6<<<512, 256, 0, stream>>>(Wh, W6);
    prep_gxd<<<(NDIG * G4 + 255) / 256, 256, 0, stream>>>(emb, Wx, b, gxd);
    // zero h0 + h1 + flags (2 MB + 32 KB contiguous)
    {
        int n4 = (2 * 1024 * 1024 + 32 * 1024) / 16;
        zero_state<<<(n4 + 255) / 256, 256, 0, stream>>>((float4*)h0, n4);
    }

    void* args[] = { (void*)&W6, (void*)&gxd, (void*)&x, (void*)&h0, (void*)&h1,
                     (void*)&flg, (void*)&Wp, (void*)&bp, (void*)&out };
    hipLaunchCooperativeKernel((void*)lstm_persist, dim3(256), dim3(512),
                               args, 0, stream);
}

// Round 10
// 829.007 us; speedup vs baseline: 1.8937x; 1.8937x over previous
//
#include <hip/hip_runtime.h>
#include <math.h>

#define Bsz  1024
#define Tlen 128
#define Hdim 512
#define NCLS 10
#define NDIG 3
#define G4   2048   // 4*H

typedef short s8v __attribute__((ext_vector_type(8)));    // 8 bf16 (4 VGPRs)
typedef float f16v __attribute__((ext_vector_type(16)));  // 32x32 mfma acc

// ---- workspace layout (bytes) ----
// W6 : 2 MB  bf16 frag chunks: uint4 idx = (wn*32+ks)*64 + lane, wn=0..63
//      lane l elem j: n = wn*32+(l&31) -> jp=n>>2,g=n&3, row=g*512+jp,
//      k = ks*16 + (l>>5)*8 + j
// gxd: 24 KB fp32 [d][jp*4+g] (padded to 32 KB)
// h0/h1: 1 MB bf16 each; per-chain 32 KB: uint4 idx = mt*2048 + ks*64 + l
//      elem j = h[b = l&31][k = ks*16 + (l>>5)*8 + j]   (32 rows x 512 k)
// gflags: 32 KB (32 chains x 8 producers, stride 32 ints): value v = h_v published
#define W6_OFF  0
#define GXD_OFF (2*1024*1024)
#define H0_OFF  (GXD_OFF + 32*1024)
#define H1_OFF  (H0_OFF + 1024*1024)
#define FLG_OFF (H1_OFF + 1024*1024)

static __device__ __forceinline__ unsigned short f2bf(float f) {
    unsigned int u = __float_as_uint(f);
    u = (u + 0x7FFFu + ((u >> 16) & 1u)) >> 16;   // RNE
    return (unsigned short)u;
}
static __device__ __forceinline__ float bf2f(unsigned short s) {
    return __uint_as_float(((unsigned int)s) << 16);
}
static __device__ __forceinline__ s8v u2s(uint4 v) {
    union { uint4 u; s8v s; } x; x.u = v; return x.s;
}

// ---- prep: W6 frag chunks (R5 layout) ----
__global__ __launch_bounds__(256) void prep_w6(const float* __restrict__ Wh,
                                               unsigned short* __restrict__ W6) {
    int idx = blockIdx.x * 256 + threadIdx.x;   // 0..131071
    int l  = idx & 63;
    int c  = idx >> 6;          // wn*32 + ks
    int ks = c & 31, wn = c >> 5;
    int n  = wn * 32 + (l & 31);
    int jp = n >> 2, g = n & 3;
    int row = g * Hdim + jp;
    int kb  = ks * 16 + (l >> 5) * 8;
    const float* src = &Wh[(size_t)row * Hdim + kb];
    unsigned int p0 = f2bf(src[0]) | ((unsigned int)f2bf(src[1]) << 16);
    unsigned int p1 = f2bf(src[2]) | ((unsigned int)f2bf(src[3]) << 16);
    unsigned int p2 = f2bf(src[4]) | ((unsigned int)f2bf(src[5]) << 16);
    unsigned int p3 = f2bf(src[6]) | ((unsigned int)f2bf(src[7]) << 16);
    ((uint4*)W6)[idx] = make_uint4(p0, p1, p2, p3);
}

__global__ __launch_bounds__(256) void prep_gxd(const float* __restrict__ emb,
                                                const float* __restrict__ Wx,
                                                const float* __restrict__ b,
                                                float* __restrict__ gxd) {
    int idx = blockIdx.x * 256 + threadIdx.x;
    if (idx >= NDIG * G4) return;
    int col = idx % G4;
    int d   = idx / G4;
    int jp  = col >> 2;
    int g   = col & 3;
    int row = g * Hdim + jp;
    gxd[idx] = emb[d * 2 + 0] * Wx[row * 2 + 0]
             + emb[d * 2 + 1] * Wx[row * 2 + 1]
             + b[row];
}

__global__ __launch_bounds__(256) void zero_state(float4* __restrict__ p, int n4) {
    int i = blockIdx.x * 256 + threadIdx.x;
    if (i < n4) p[i] = make_float4(0.f, 0.f, 0.f, 0.f);
}

// ---- persistent LSTM: R5 lockstep skeleton + z^T epilogue + producer flags ----
// 256 blocks x 512 thr (1/CU). mt = blk&31 (chain: 32 rows), nt = blk>>5
// (256 gate-cols = 64 jp). Chain of 8 blocks. Per step: 2 __syncthreads.
// MFMA computes z^T = W.h^T (W = A-operand) so all 4 gates of (b,jp) land in
// one lane -> in-register epilogue (R9-verified math).
__global__ __launch_bounds__(512, 2) void lstm_persist(
    const uint4* __restrict__ W6, const float* __restrict__ gxd,
    const int* __restrict__ x, uint4* __restrict__ h0, uint4* __restrict__ h1,
    int* __restrict__ gflags, const float* __restrict__ Wp,
    const float* __restrict__ bp, float* __restrict__ out)
{
    __shared__ uint4 h_lds[2048];       // 32 KB  h B-frags (single buffer)
    __shared__ float gxd_s[NDIG * G4];  // 24 KB
    __shared__ int   x_s[4096];         // 16 KB  [t][b_local]

    const int tid  = threadIdx.x;
    const int w    = tid >> 6;          // wave 0..7
    const int lane = tid & 63;
    const int hi   = lane >> 5;
    const int bl   = lane & 31;         // batch row (C col)
    const int mt   = blockIdx.x & 31;
    const int nt   = blockIdx.x >> 5;

    // A-resident W fragments: wave n-window = nt*256 + w*32 (32 gate-cols)
    s8v wfrag[32];
    {
        const uint4* wq = W6 + (size_t)((nt * 8 + w) * 32) * 64 + lane;
#pragma unroll
        for (int ks = 0; ks < 32; ks++) wfrag[ks] = u2s(wq[ks * 64]);
    }
    for (int i = tid; i < 4096; i += 512) {
        int b2 = i & 31, tt = i >> 5;
        x_s[tt * 32 + b2] = x[(mt * 32 + b2) * Tlen + tt];
    }
    for (int i = tid; i < NDIG * G4; i += 512) gxd_s[i] = gxd[i];
    __syncthreads();   // one-time init

    float c0 = 0.f, c1 = 0.f, c2 = 0.f, c3 = 0.f;
    const int jbase = nt * 64 + w * 8 + hi;           // jp for u: jbase + 2u
    const long hsull = ((long)mt * 2048 + (nt * 4 + (w >> 1)) * 64
                        + (w & 1) * 32 + bl) * 2 + hi;
    int* myflag = gflags + (mt * 8 + nt) * 32;        // this block's flag
    const int* stgflag = gflags + (mt * 8 + w) * 32;  // wave-w's producer flag

#pragma unroll 1
    for (int t = 0; t < Tlen; t++) {
        const int par = t & 1;
        const uint4* hr = par ? h1 : h0;   // h_t
        uint4*       hw = par ? h0 : h1;   // h_{t+1}

        // ---- stage: wave w loads producer-w's 4 KB slice once published ----
        {
            if (lane == 0) {
                while (__hip_atomic_load(stgflag, __ATOMIC_RELAXED,
                                         __HIP_MEMORY_SCOPE_AGENT) < t)
                    __builtin_amdgcn_s_sleep(1);
            }
            // wave reconverges here; loads depend on the branch exit
            const unsigned long long* hr8 =
                (const unsigned long long*)(hr + mt * 2048);
            unsigned long long* hl8 = (unsigned long long*)h_lds;
#pragma unroll
            for (int s = 0; s < 8; s++) {
                int o = w * 512 + s * 64 + lane;
                hl8[o] = __hip_atomic_load(hr8 + o, __ATOMIC_RELAXED,
                                           __HIP_MEMORY_SCOPE_AGENT);
            }
            asm volatile("s_waitcnt lgkmcnt(0) vmcnt(0)" ::: "memory");
        }
        __syncthreads();                   // sync1: all 8 slices in LDS

        // ---- K loop: z^T tile (W = A from regs, h = B from LDS) ----
        f16v acc = {0,0,0,0,0,0,0,0,0,0,0,0,0,0,0,0};
#pragma unroll
        for (int ks = 0; ks < 32; ks++) {
            s8v hf = u2s(h_lds[ks * 64 + lane]);
            acc = __builtin_amdgcn_mfma_f32_32x32x16_bf16(wfrag[ks], hf, acc,
                                                          0, 0, 0);
        }

        // ---- in-register epilogue: lane = (b=bl, jp=jbase+2u, 4 gates) ----
        {
            int d = x_s[t * 32 + bl];
            float cc[4] = {c0, c1, c2, c3};
            unsigned short hh[4];
#pragma unroll
            for (int u = 0; u < 4; u++) {
                int jp = jbase + 2 * u;
                float4 g4 = *(const float4*)&gxd_s[d * G4 + jp * 4];
                float zg = acc[4*u+0] + g4.x;
                float zi = acc[4*u+1] + g4.y;
                float zf = acc[4*u+2] + g4.z;
                float zo = acc[4*u+3] + g4.w;
                float gv = 1.f - 2.f / (__expf(2.f * zg) + 1.f);
                float iv = 1.f / (1.f + __expf(-zi));
                float fv = 1.f / (1.f + __expf(-zf));
                float ov = 1.f / (1.f + __expf(-zo));
                float cn = gv * iv + cc[u] * fv;
                cc[u] = cn;
                hh[u] = f2bf((1.f - 2.f / (__expf(2.f * cn) + 1.f)) * ov);
            }
            c0 = cc[0]; c1 = cc[1]; c2 = cc[2]; c3 = cc[3];
            // repack even/odd jp across hi-halves -> 4 contiguous bf16 (8B)
            unsigned int p01 = (unsigned int)hh[0] | ((unsigned int)hh[1] << 16);
            unsigned int p23 = (unsigned int)hh[2] | ((unsigned int)hh[3] << 16);
            unsigned int q01 = __shfl_xor(p01, 32);
            unsigned int q23 = __shfl_xor(p23, 32);
            unsigned long long hv;
            if (hi == 0) {
                unsigned int lo2 = (p01 & 0xffffu) | ((q01 & 0xffffu) << 16);
                unsigned int hi2 = (p01 >> 16) | (q01 & 0xffff0000u);
                hv = (unsigned long long)lo2 | ((unsigned long long)hi2 << 32);
            } else {
                unsigned int lo2 = (q23 & 0xffffu) | ((p23 & 0xffffu) << 16);
                unsigned int hi2 = (q23 >> 16) | (p23 & 0xffff0000u);
                hv = (unsigned long long)lo2 | ((unsigned long long)hi2 << 32);
            }
            __hip_atomic_store((unsigned long long*)hw + hsull, hv,
                               __ATOMIC_RELAXED, __HIP_MEMORY_SCOPE_AGENT);
        }

        // ---- drain + publish: single-writer flag after block-wide sync ----
        asm volatile("s_waitcnt vmcnt(0)" ::: "memory");
        __syncthreads();                   // sync2: reads done + stores drained
        if (tid == 0)
            __hip_atomic_store(myflag, t + 1, __ATOMIC_RELAXED,
                               __HIP_MEMORY_SCOPE_AGENT);
    }

    // ---- head (nt==0 blocks): p = h.Wp + bp, log_softmax for 32 rows ----
    if (nt != 0) return;
    if (tid < 8) {
        const int* gf = gflags + (mt * 8 + tid) * 32;
        while (__hip_atomic_load(gf, __ATOMIC_RELAXED,
                                 __HIP_MEMORY_SCOPE_AGENT) < Tlen)
            __builtin_amdgcn_s_sleep(1);
    }
    __syncthreads();
    float* wp_s = gxd_s;   // 20 KB into 24 KB region
    for (int i = tid; i < Hdim * NCLS; i += 512) wp_s[i] = Wp[i];
    __syncthreads();

    const unsigned long long* hf8 =
        (const unsigned long long*)(h0 + mt * 2048);   // h_128 in buf0
#pragma unroll
    for (int rr = 0; rr < 4; rr++) {
        int blr = w * 4 + rr;
        int b   = mt * 32 + blr;
        int u4 = (lane >> 1) * 64 + (lane & 1) * 32 + blr;
        unsigned long long lo = __hip_atomic_load(hf8 + u4 * 2,
            __ATOMIC_RELAXED, __HIP_MEMORY_SCOPE_AGENT);
        unsigned long long hi2 = __hip_atomic_load(hf8 + u4 * 2 + 1,
            __ATOMIC_RELAXED, __HIP_MEMORY_SCOPE_AGENT);
        union { unsigned long long q[2]; unsigned short s[8]; } hu;
        hu.q[0] = lo; hu.q[1] = hi2;
        float a[NCLS];
#pragma unroll
        for (int c = 0; c < NCLS; c++) a[c] = 0.f;
#pragma unroll
        for (int j = 0; j < 8; j++) {
            int k = lane * 8 + j;
            float hvv = bf2f(hu.s[j]);
#pragma unroll
            for (int c = 0; c < NCLS; c++) a[c] += hvv * wp_s[k * NCLS + c];
        }
#pragma unroll
        for (int off = 32; off > 0; off >>= 1) {
#pragma unroll
            for (int c = 0; c < NCLS; c++) a[c] += __shfl_down(a[c], off);
        }
        if (lane == 0) {
            float p[NCLS], m = -1e30f;
#pragma unroll
            for (int c = 0; c < NCLS; c++) { p[c] = a[c] + bp[c]; m = fmaxf(m, p[c]); }
            float s = 0.f;
#pragma unroll
            for (int c = 0; c < NCLS; c++) s += __expf(p[c] - m);
            float lse = m + logf(s);
#pragma unroll
            for (int c = 0; c < NCLS; c++) out[b * NCLS + c] = p[c] - lse;
        }
    }
}

extern "C" void kernel_launch(void* const* d_in, const int* in_sizes, int n_in,
                              void* d_out, int out_size, void* d_ws, size_t ws_size,
                              hipStream_t stream) {
    const int*   x   = (const int*)d_in[0];
    const float* emb = (const float*)d_in[1];
    const float* Wx  = (const float*)d_in[2];
    const float* Wh  = (const float*)d_in[3];
    const float* b   = (const float*)d_in[4];
    const float* Wp  = (const float*)d_in[5];
    const float* bp  = (const float*)d_in[6];
    float* out = (float*)d_out;
    char*  ws  = (char*)d_ws;

    unsigned short* W6  = (unsigned short*)(ws + W6_OFF);
    float*          gxd = (float*)(ws + GXD_OFF);
    uint4*          h0  = (uint4*)(ws + H0_OFF);
    uint4*          h1  = (uint4*)(ws + H1_OFF);
    int*            flg = (int*)(ws + FLG_OFF);

    prep_w6<<<512, 256, 0, stream>>>(Wh, W6);
    prep_gxd<<<(NDIG * G4 + 255) / 256, 256, 0, stream>>>(emb, Wx, b, gxd);
    // zero h0 + h1 + flags (2 MB + 32 KB contiguous)
    {
        int n4 = (2 * 1024 * 1024 + 32 * 1024) / 16;
        zero_state<<<(n4 + 255) / 256, 256, 0, stream>>>((float4*)h0, n4);
    }

    void* args[] = { (void*)&W6, (void*)&gxd, (void*)&x, (void*)&h0, (void*)&h1,
                     (void*)&flg, (void*)&Wp, (void*)&bp, (void*)&out };
    hipLaunchCooperativeKernel((void*)lstm_persist, dim3(256), dim3(512),
                               args, 0, stream);
}